// Round 14
// baseline (116.378 us; speedup 1.0000x reference)
//
#include <hip/hip_runtime.h>
#include <math.h>

#define NU 32768
#define NI 16384
#define DH 64
#define KK 50

typedef unsigned short ushort_t;
typedef __attribute__((ext_vector_type(8))) short  bf16x8;
typedef __attribute__((ext_vector_type(4))) float  f32x4;
typedef __attribute__((ext_vector_type(4))) unsigned int u32x4;

__device__ __forceinline__ unsigned cvtpk(float lo, float hi) {
    unsigned r;
    asm("v_cvt_pk_bf16_f32 %0, %1, %2" : "=v"(r) : "v"(lo), "v"(hi));
    return r;
}
__device__ __forceinline__ bf16x8 as_bf(u32x4 v) {
    union { u32x4 u; bf16x8 b; } x; x.u = v; return x.b;
}
__device__ __forceinline__ ushort_t bf16r(float v) {
    unsigned u = __float_as_uint(v);
    u += 0x7fffu + ((u >> 16) & 1u);
    return (ushort_t)(u >> 16);
}
__device__ __forceinline__ u32x4 pk8(const float* p) {
    float4 a = *(const float4*)p;
    float4 b = *(const float4*)(p + 4);
    u32x4 r;
    r[0] = cvtpk(a.x, a.y); r[1] = cvtpk(a.z, a.w);
    r[2] = cvtpk(b.x, b.y); r[3] = cvtpk(b.z, b.w);
    return r;
}

// ---------------------------------------------------------------------------
// projprep: blocks [0,768) = proj via MFMA; blocks 768/769 = prep.
// (byte-identical to R8/R10/R12/R13 — verified)
// ---------------------------------------------------------------------------
__global__ __launch_bounds__(256) void projprep_kernel(
    const float* __restrict__ user_feat, const float* __restrict__ item_feat,
    const float* __restrict__ W_user,    const float* __restrict__ W_item,
    const float* __restrict__ gate_u,    const float* __restrict__ gate_i,
    const float* __restrict__ u_te,      const float* __restrict__ i_te,
    const float* __restrict__ u_te_k,    const float* __restrict__ i_te_k,
    ushort_t* __restrict__ hbf_u, ushort_t* __restrict__ hbf_i,
    ushort_t* __restrict__ teA_u, ushort_t* __restrict__ teA_i,
    ushort_t* __restrict__ gA_u,  ushort_t* __restrict__ gA_i)
{
    __shared__ __align__(16) float SH[3200];
    const int b    = blockIdx.x;
    const int tid  = threadIdx.x;
    const int w    = tid >> 6;
    const int lane = tid & 63;
    const int c = lane & 15, g = lane >> 4;

    if (b < 768) {
        const bool isU = b < 512;
        const float* feat = isU ? user_feat : item_feat;
        const float* W    = isU ? W_user    : W_item;
        ushort_t*    hbf  = isU ? hbf_u     : hbf_i;
        const int    bb   = isU ? b : b - 512;

        ushort_t* WA = (ushort_t*)SH;
        for (int i = tid; i < 4096; i += 256) {
            int j = i & 7, l = (i >> 3) & 63, s = (i >> 9) & 1, mt = i >> 10;
            int row = mt * 16 + (l & 15);
            int k   = s * 32 + ((l >> 4) & 3) * 8 + j;
            WA[i] = bf16r(W[row * DH + k]);
        }
        __syncthreads();

        const int nb = bb * 64 + w * 16;
        u32x4 bf[2];
        #pragma unroll
        for (int s = 0; s < 2; ++s)
            bf[s] = pk8(feat + (size_t)(nb + c) * DH + s * 32 + g * 8);

        #pragma unroll
        for (int mt = 0; mt < 4; ++mt) {
            f32x4 acc = {0.f, 0.f, 0.f, 0.f};
            #pragma unroll
            for (int s = 0; s < 2; ++s) {
                u32x4 af = *(const u32x4*)(WA + ((mt * 2 + s) * 64 + lane) * 8);
                acc = __builtin_amdgcn_mfma_f32_16x16x32_bf16(as_bf(af), as_bf(bf[s]), acc, 0, 0, 0);
            }
            uint2 p;
            p.x = cvtpk(acc[0], acc[1]);
            p.y = cvtpk(acc[2], acc[3]);
            *(uint2*)(hbf + (size_t)(nb + c) * DH + mt * 16 + g * 4) = p;
        }
    } else {
        const int rel = b - 768;
        const float* gate = rel ? gate_i : gate_u;
        const float* te   = rel ? i_te   : u_te;
        const float* tek  = rel ? i_te_k : u_te_k;
        ushort_t* teA = rel ? teA_i : teA_u;
        ushort_t* gA  = rel ? gA_i  : gA_u;
        float* M = SH;

        {
            const int d = w * 16 + c;
            u32x4 ga[2];
            #pragma unroll
            for (int s = 0; s < 2; ++s)
                ga[s] = pk8(gate + (size_t)d * 128 + s * 32 + g * 8);
            #pragma unroll
            for (int rt = 0; rt < 4; ++rt) {
                int r = rt * 16 + c;
                const float* tr = tek + (size_t)(r < KK ? r : 0) * DH;
                f32x4 acc = {0.f, 0.f, 0.f, 0.f};
                #pragma unroll
                for (int s = 0; s < 2; ++s) {
                    u32x4 bfr = pk8(tr + s * 32 + g * 8);
                    acc = __builtin_amdgcn_mfma_f32_16x16x32_bf16(as_bf(ga[s]), as_bf(bfr), acc, 0, 0, 0);
                }
                if (r < KK) {
                    #pragma unroll
                    for (int jj = 0; jj < 4; ++jj)
                        M[(w * 16 + g * 4 + jj) * KK + r] = acc[jj];
                }
            }
        }
        __syncthreads();

        for (int i = tid; i < 4096; i += 256) {
            int j = i & 7, l = (i >> 3) & 63, s = (i >> 9) & 1, t = i >> 10;
            int r = t * 16 + (l & 15);
            int d = s * 32 + ((l >> 4) & 3) * 8 + j;
            teA[i] = bf16r(r < KK ? te[r * DH + d] : 0.f);
        }
        for (int i = tid; i < 12288; i += 256) {
            int j = i & 7, l = (i >> 3) & 63, q = i >> 9;
            int s = q % 6, mt = q / 6;
            int d = mt * 16 + (l & 15);
            int k = s * 32 + ((l >> 4) & 3) * 8 + j;
            float v = 0.f;
            if (k < 128)            v = gate[d * 128 + k];
            else if (k < 128 + KK)  v = M[d * KK + (k - 128)];
            gA[i] = bf16r(v);
        }
    }
}

// ---------------------------------------------------------------------------
// agg: per-relation. 128 threads = 2 waves = 2 nodes, no __syncthreads.
// R13 base + (1) sle B-frag read directly from swizzled LDS mail (row `last`,
// one b128 per s — same addr formula as the writer, conflict-free), and
// (2) f32 dual-readlane alphas in the weighted loop (no pack/unpack).
// ---------------------------------------------------------------------------
__global__ __launch_bounds__(128) void agg_kernel(
    const ushort_t* __restrict__ h_src,
    const ushort_t* __restrict__ h_dst,
    const int*      __restrict__ nbr,
    const int*      __restrict__ times,
    const ushort_t* __restrict__ teA,
    ushort_t*       __restrict__ ccout)
{
    __shared__ __align__(16) char SM[2][7168];

    const int wid  = threadIdx.x >> 6;
    const int lane = threadIdx.x & 63;
    const int n    = blockIdx.x * 2 + wid;

    char*  mailb = SM[wid];                   // [50 rows][128 B], granule-swizzled
    float* EB    = (float*)(SM[wid] + 6400);  // e[64] e1[64] tp[64]
    const int c = lane & 15;
    const int g = lane >> 4;

    int my_t = 0, my_nb = 0;
    if (lane < KK) {
        my_t  = times[n * KK + lane];
        my_nb = nbr[n * KK + lane];
    }

    // ---- gather register A-frags (verified layout) + LDS mail copy ----
    // element (row r, d): stored at r*128 + (((d>>3)^(r&7))<<4) + (d&7)*2
    u32x4 af[4][2];
    #pragma unroll
    for (int t = 0; t < 4; ++t) {
        int r = t * 16 + c;
        int idx = __builtin_amdgcn_ds_bpermute(r << 2, my_nb);
        const ushort_t* src = h_src + idx * DH;
        #pragma unroll
        for (int s = 0; s < 2; ++s) {
            u32x4 v = *(const u32x4*)(src + s * 32 + g * 8);
            af[t][s] = v;
            if (t < 3 || c < 2) {   // rows < 50 only
                unsigned bo = (unsigned)(r * 128)
                            + (unsigned)(((4 * s + g) ^ (c & 7)) << 4);
                *(u32x4*)(mailb + bo) = v;
            }
        }
    }

    // ---- stable ranks ----
    int key = my_t * 64 + lane;
    int sro = 0;
    #pragma unroll
    for (int j = 0; j < KK; ++j) {
        int kj = __builtin_amdgcn_readlane(key, j);
        sro += (kj > key) ? 1 : 0;
    }

    // ---- last = first argmax(times) ----
    int key2 = (lane < KK) ? (my_t * 64 + (63 - lane)) : -1;
    #pragma unroll
    for (int off = 32; off >= 1; off >>= 1) {
        int o = __shfl_xor(key2, off);
        key2 = key2 > o ? key2 : o;
    }
    const int last = __builtin_amdgcn_readfirstlane(63 - (key2 & 63));

    // ---- B-fragments: col0 = dst(bf16), col1 = sle = mail[last] from LDS ----
    u32x4 fbv[2];
    {
        const ushort_t* hd = h_dst + n * DH;
        #pragma unroll
        for (int s = 0; s < 2; ++s) {
            u32x4 dp = *(const u32x4*)(hd + s * 32 + g * 8);
            unsigned sbyte = (unsigned)(last * 128)
                           + (unsigned)((((4 * s + g) ^ (last & 7)) << 4));
            u32x4 sl = *(const u32x4*)(mailb + sbyte);
            fbv[s] = (c == 1) ? sl : dp;
        }
    }

    // ---- dot MFMA: e (col0), e1 (col1) ----
    #pragma unroll
    for (int t = 0; t < 4; ++t) {
        f32x4 acc = {0.f, 0.f, 0.f, 0.f};
        #pragma unroll
        for (int s = 0; s < 2; ++s)
            acc = __builtin_amdgcn_mfma_f32_16x16x32_bf16(as_bf(af[t][s]), as_bf(fbv[s]), acc, 0, 0, 0);
        if (c < 2) {
            float* eb = EB + c * 64 + t * 16 + g * 4;
            eb[0] = acc[0]; eb[1] = acc[1]; eb[2] = acc[2]; eb[3] = acc[3];
        }
    }

    // ---- tp MFMA (teA tiles) ----
    #pragma unroll
    for (int t = 0; t < 4; ++t) {
        f32x4 acc = {0.f, 0.f, 0.f, 0.f};
        #pragma unroll
        for (int s = 0; s < 2; ++s) {
            u32x4 ta = *(const u32x4*)(teA + ((t * 2 + s) * 64 + lane) * 8);
            acc = __builtin_amdgcn_mfma_f32_16x16x32_bf16(as_bf(ta), as_bf(fbv[s]), acc, 0, 0, 0);
        }
        if (c == 0) {
            float* eb = EB + 128 + t * 16 + g * 4;
            eb[0] = acc[0]; eb[1] = acc[1]; eb[2] = acc[2]; eb[3] = acc[3];
        }
    }

    // ---- softmax at lane = k ----
    float eraw  = EB[lane];
    float e1raw = EB[64 + lane];
    float tpown = EB[128 + lane];
    float tps = __uint_as_float(__builtin_amdgcn_ds_bpermute(sro << 2, __float_as_uint(tpown)));
    float e  = (lane < KK) ? (eraw + tps) * 0.125f : -INFINITY;
    float e1 = (lane < KK) ? e1raw * 0.125f        : -INFINITY;
    float m = e, m1 = e1;
    #pragma unroll
    for (int off = 32; off >= 1; off >>= 1) {
        m  = fmaxf(m,  __shfl_xor(m,  off));
        m1 = fmaxf(m1, __shfl_xor(m1, off));
    }
    float p  = (lane < KK) ? __expf(e - m)   : 0.f;
    float p1 = (lane < KK) ? __expf(e1 - m1) : 0.f;
    float s = p, s1 = p1;
    #pragma unroll
    for (int off = 32; off >= 1; off >>= 1) {
        s  += __shfl_xor(s,  off);
        s1 += __shfl_xor(s1, off);
    }
    float al  = p  * __builtin_amdgcn_rcpf(s);
    float al1 = p1 * __builtin_amdgcn_rcpf(s1);

    // ---- beta scatter + cc store ----
    ushort_t* ccr = ccout + (size_t)n * 192;
    {
        int pushaddr = ((lane < KK) ? sro : lane) << 2;
        float beta = __uint_as_float(__builtin_amdgcn_ds_permute(pushaddr, __float_as_uint(al)));
        ccr[128 + lane] = bf16r(beta);
    }

    // ---- weighted sums (lane = d): LDS mail reads + f32 dual-readlane alphas ----
    int voff[8];
    #pragma unroll
    for (int q = 0; q < 8; ++q)
        voff[q] = (((lane >> 3) ^ q) << 4) + (lane & 7) * 2;
    float hl = 0.f, hs = 0.f;
    #pragma unroll
    for (int k = 0; k < KK; ++k) {
        float a  = __uint_as_float(__builtin_amdgcn_readlane(__float_as_uint(al),  k));
        float a1 = __uint_as_float(__builtin_amdgcn_readlane(__float_as_uint(al1), k));
        ushort_t u = *(const ushort_t*)(mailb + k * 128 + voff[k & 7]);
        float mv = __uint_as_float(((unsigned)u) << 16);
        hl = fmaf(a,  mv, hl);
        hs = fmaf(a1, mv, hs);
    }
    unsigned hp = cvtpk(hl, hs);
    ccr[lane]      = (ushort_t)hp;
    ccr[64 + lane] = (ushort_t)(hp >> 16);
}

// ---------------------------------------------------------------------------
// epi: combined item+user batched gate GEMM. 1 wave = 16 nodes.
// (byte-identical to R12/R13 — verified)
// ---------------------------------------------------------------------------
__global__ __launch_bounds__(256) void epi_kernel(
    const ushort_t* __restrict__ cc_i, const ushort_t* __restrict__ cc_u,
    const ushort_t* __restrict__ gA_i, const ushort_t* __restrict__ gA_u,
    const float* __restrict__ item_feat, const float* __restrict__ user_feat,
    float* __restrict__ item_out, float* __restrict__ user_out)
{
    const int b = blockIdx.x;
    const bool isU = b >= (NI / 64);
    const ushort_t* cc   = isU ? cc_u : cc_i;
    const ushort_t* gA   = isU ? gA_u : gA_i;
    const float*    feat = isU ? user_feat : item_feat;
    float*          out  = isU ? user_out  : item_out;
    const int bb = isU ? b - NI / 64 : b;

    const int w    = threadIdx.x >> 6;
    const int lane = threadIdx.x & 63;
    const int c = lane & 15, g = lane >> 4;
    const int nb = bb * 64 + w * 16;

    const char* ccr = (const char*)(cc + (size_t)(nb + c) * 192);
    u32x4 bb6[6];
    #pragma unroll
    for (int s = 0; s < 6; ++s)
        bb6[s] = *(const u32x4*)(ccr + s * 64 + g * 16);

    f32x4 acc[4] = {{0,0,0,0},{0,0,0,0},{0,0,0,0},{0,0,0,0}};
    #pragma unroll
    for (int mt = 0; mt < 4; ++mt)
        #pragma unroll
        for (int s = 0; s < 6; ++s) {
            u32x4 ga = *(const u32x4*)(gA + (size_t)((mt * 6 + s) * 64 + lane) * 8);
            acc[mt] = __builtin_amdgcn_mfma_f32_16x16x32_bf16(as_bf(ga), as_bf(bb6[s]), acc[mt], 0, 0, 0);
        }

    const float* fr   = feat + (size_t)(nb + c) * 64;
    float*       orow = out  + (size_t)(nb + c) * 64;
    #pragma unroll
    for (int mt = 0; mt < 4; ++mt) {
        float4 f4 = *(const float4*)(fr + mt * 16 + g * 4);
        float4 o;
        float v0 = acc[mt][0] + f4.x; o.x = v0 > 0.f ? v0 : (__expf(v0) - 1.f);
        float v1 = acc[mt][1] + f4.y; o.y = v1 > 0.f ? v1 : (__expf(v1) - 1.f);
        float v2 = acc[mt][2] + f4.z; o.z = v2 > 0.f ? v2 : (__expf(v2) - 1.f);
        float v3 = acc[mt][3] + f4.w; o.w = v3 > 0.f ? v3 : (__expf(v3) - 1.f);
        *(float4*)(orow + mt * 16 + g * 4) = o;
    }
}

extern "C" void kernel_launch(void* const* d_in, const int* in_sizes, int n_in,
                              void* d_out, int out_size, void* d_ws, size_t ws_size,
                              hipStream_t stream) {
    const float* user_feat = (const float*)d_in[0];
    const float* item_feat = (const float*)d_in[1];
    const float* W_user    = (const float*)d_in[2];
    const float* W_item    = (const float*)d_in[3];
    const float* gate_u    = (const float*)d_in[4];
    const float* gate_i    = (const float*)d_in[5];
    const float* u_te      = (const float*)d_in[6];
    const float* u_te_k    = (const float*)d_in[7];
    const float* i_te      = (const float*)d_in[8];
    const float* i_te_k    = (const float*)d_in[9];
    const int*   user_nbr  = (const int*)d_in[10];
    const int*   item_nbr  = (const int*)d_in[11];
    const int*   user_time = (const int*)d_in[12];
    const int*   item_time = (const int*)d_in[13];

    ushort_t* hbf_u = (ushort_t*)d_ws;            // NU*64
    ushort_t* hbf_i = hbf_u + NU * DH;            // NI*64
    ushort_t* teA_u = hbf_i + NI * DH;            // 4096
    ushort_t* teA_i = teA_u + 4096;               // 4096
    ushort_t* gA_u  = teA_i + 4096;               // 12288
    ushort_t* gA_i  = gA_u + 12288;               // 12288
    ushort_t* cc_i  = gA_i + 12288;               // NI*192
    ushort_t* cc_u  = cc_i + (size_t)NI * 192;    // NU*192

    float* user_out = (float*)d_out;
    float* item_out = user_out + NU * DH;

    hipLaunchKernelGGL(projprep_kernel, dim3(770), dim3(256), 0, stream,
                       user_feat, item_feat, W_user, W_item, gate_u, gate_i,
                       u_te, i_te, u_te_k, i_te_k,
                       hbf_u, hbf_i, teA_u, teA_i, gA_u, gA_i);
    hipLaunchKernelGGL(agg_kernel, dim3(NI / 2), dim3(128), 0, stream,
                       hbf_u, hbf_i, item_nbr, item_time, teA_i, cc_i);
    hipLaunchKernelGGL(agg_kernel, dim3(NU / 2), dim3(128), 0, stream,
                       hbf_i, hbf_u, user_nbr, user_time, teA_u, cc_u);
    hipLaunchKernelGGL(epi_kernel, dim3(NI / 64 + NU / 64), dim3(256), 0, stream,
                       cc_i, cc_u, gA_i, gA_u, item_feat, user_feat,
                       item_out, user_out);
}

// Round 15
// 109.485 us; speedup vs baseline: 1.0630x; 1.0630x over previous
//
#include <hip/hip_runtime.h>
#include <math.h>

#define NU 32768
#define NI 16384
#define DH 64
#define KK 50

typedef unsigned short ushort_t;
typedef __attribute__((ext_vector_type(8))) short  bf16x8;
typedef __attribute__((ext_vector_type(4))) float  f32x4;
typedef __attribute__((ext_vector_type(4))) unsigned int u32x4;

__device__ __forceinline__ unsigned cvtpk(float lo, float hi) {
    unsigned r;
    asm("v_cvt_pk_bf16_f32 %0, %1, %2" : "=v"(r) : "v"(lo), "v"(hi));
    return r;
}
__device__ __forceinline__ bf16x8 as_bf(u32x4 v) {
    union { u32x4 u; bf16x8 b; } x; x.u = v; return x.b;
}
__device__ __forceinline__ ushort_t bf16r(float v) {
    unsigned u = __float_as_uint(v);
    u += 0x7fffu + ((u >> 16) & 1u);
    return (ushort_t)(u >> 16);
}
__device__ __forceinline__ u32x4 pk8(const float* p) {
    float4 a = *(const float4*)p;
    float4 b = *(const float4*)(p + 4);
    u32x4 r;
    r[0] = cvtpk(a.x, a.y); r[1] = cvtpk(a.z, a.w);
    r[2] = cvtpk(b.x, b.y); r[3] = cvtpk(b.z, b.w);
    return r;
}

// ---------------------------------------------------------------------------
// projprep: blocks [0,768) = proj via MFMA; blocks 768/769 = prep.
// (byte-identical to R8/R10/R12/R13/R14 — verified)
// ---------------------------------------------------------------------------
__global__ __launch_bounds__(256) void projprep_kernel(
    const float* __restrict__ user_feat, const float* __restrict__ item_feat,
    const float* __restrict__ W_user,    const float* __restrict__ W_item,
    const float* __restrict__ gate_u,    const float* __restrict__ gate_i,
    const float* __restrict__ u_te,      const float* __restrict__ i_te,
    const float* __restrict__ u_te_k,    const float* __restrict__ i_te_k,
    ushort_t* __restrict__ hbf_u, ushort_t* __restrict__ hbf_i,
    ushort_t* __restrict__ teA_u, ushort_t* __restrict__ teA_i,
    ushort_t* __restrict__ gA_u,  ushort_t* __restrict__ gA_i)
{
    __shared__ __align__(16) float SH[3200];
    const int b    = blockIdx.x;
    const int tid  = threadIdx.x;
    const int w    = tid >> 6;
    const int lane = tid & 63;
    const int c = lane & 15, g = lane >> 4;

    if (b < 768) {
        const bool isU = b < 512;
        const float* feat = isU ? user_feat : item_feat;
        const float* W    = isU ? W_user    : W_item;
        ushort_t*    hbf  = isU ? hbf_u     : hbf_i;
        const int    bb   = isU ? b : b - 512;

        ushort_t* WA = (ushort_t*)SH;
        for (int i = tid; i < 4096; i += 256) {
            int j = i & 7, l = (i >> 3) & 63, s = (i >> 9) & 1, mt = i >> 10;
            int row = mt * 16 + (l & 15);
            int k   = s * 32 + ((l >> 4) & 3) * 8 + j;
            WA[i] = bf16r(W[row * DH + k]);
        }
        __syncthreads();

        const int nb = bb * 64 + w * 16;
        u32x4 bf[2];
        #pragma unroll
        for (int s = 0; s < 2; ++s)
            bf[s] = pk8(feat + (size_t)(nb + c) * DH + s * 32 + g * 8);

        #pragma unroll
        for (int mt = 0; mt < 4; ++mt) {
            f32x4 acc = {0.f, 0.f, 0.f, 0.f};
            #pragma unroll
            for (int s = 0; s < 2; ++s) {
                u32x4 af = *(const u32x4*)(WA + ((mt * 2 + s) * 64 + lane) * 8);
                acc = __builtin_amdgcn_mfma_f32_16x16x32_bf16(as_bf(af), as_bf(bf[s]), acc, 0, 0, 0);
            }
            uint2 p;
            p.x = cvtpk(acc[0], acc[1]);
            p.y = cvtpk(acc[2], acc[3]);
            *(uint2*)(hbf + (size_t)(nb + c) * DH + mt * 16 + g * 4) = p;
        }
    } else {
        const int rel = b - 768;
        const float* gate = rel ? gate_i : gate_u;
        const float* te   = rel ? i_te   : u_te;
        const float* tek  = rel ? i_te_k : u_te_k;
        ushort_t* teA = rel ? teA_i : teA_u;
        ushort_t* gA  = rel ? gA_i  : gA_u;
        float* M = SH;

        {
            const int d = w * 16 + c;
            u32x4 ga[2];
            #pragma unroll
            for (int s = 0; s < 2; ++s)
                ga[s] = pk8(gate + (size_t)d * 128 + s * 32 + g * 8);
            #pragma unroll
            for (int rt = 0; rt < 4; ++rt) {
                int r = rt * 16 + c;
                const float* tr = tek + (size_t)(r < KK ? r : 0) * DH;
                f32x4 acc = {0.f, 0.f, 0.f, 0.f};
                #pragma unroll
                for (int s = 0; s < 2; ++s) {
                    u32x4 bfr = pk8(tr + s * 32 + g * 8);
                    acc = __builtin_amdgcn_mfma_f32_16x16x32_bf16(as_bf(ga[s]), as_bf(bfr), acc, 0, 0, 0);
                }
                if (r < KK) {
                    #pragma unroll
                    for (int jj = 0; jj < 4; ++jj)
                        M[(w * 16 + g * 4 + jj) * KK + r] = acc[jj];
                }
            }
        }
        __syncthreads();

        for (int i = tid; i < 4096; i += 256) {
            int j = i & 7, l = (i >> 3) & 63, s = (i >> 9) & 1, t = i >> 10;
            int r = t * 16 + (l & 15);
            int d = s * 32 + ((l >> 4) & 3) * 8 + j;
            teA[i] = bf16r(r < KK ? te[r * DH + d] : 0.f);
        }
        for (int i = tid; i < 12288; i += 256) {
            int j = i & 7, l = (i >> 3) & 63, q = i >> 9;
            int s = q % 6, mt = q / 6;
            int d = mt * 16 + (l & 15);
            int k = s * 32 + ((l >> 4) & 3) * 8 + j;
            float v = 0.f;
            if (k < 128)            v = gate[d * 128 + k];
            else if (k < 128 + KK)  v = M[d * KK + (k - 128)];
            gA[i] = bf16r(v);
        }
    }
}

// ---------------------------------------------------------------------------
// agg: merged item+user with XCD-aware work split. Round-robin block->XCD
// (xcd = blockIdx & 7, measured): XCDs 0-2 -> item blocks (gather table
// hbf_u 4MB fits per-XCD L2), XCDs 2-7 -> user blocks (hbf_i 2MB fits).
// Bijective: 8192 item + 16384 user blocks, 3072 blocks/XCD balanced.
// Body byte-identical to R14 (verified).
// ---------------------------------------------------------------------------
__global__ __launch_bounds__(128) void agg_kernel(
    const ushort_t* __restrict__ hbf_u, const ushort_t* __restrict__ hbf_i,
    const int* __restrict__ item_nbr,  const int* __restrict__ item_time,
    const int* __restrict__ user_nbr,  const int* __restrict__ user_time,
    const ushort_t* __restrict__ teA_u, const ushort_t* __restrict__ teA_i,
    ushort_t* __restrict__ cc_i, ushort_t* __restrict__ cc_u)
{
    __shared__ __align__(16) char SM[2][7168];

    const int wid  = threadIdx.x >> 6;
    const int lane = threadIdx.x & 63;

    // ---- XCD-aware work mapping ----
    const int b  = blockIdx.x;
    const int r8 = b & 7;
    const int sl = b >> 3;
    bool isI;
    int nodeblk;
    if (r8 < 2)            { isI = true;  nodeblk = r8 * 3072 + sl; }
    else if (r8 == 2) {
        if (sl < 2048)     { isI = true;  nodeblk = 6144 + sl; }
        else               { isI = false; nodeblk = sl - 2048; }
    }
    else                   { isI = false; nodeblk = 1024 + (r8 - 3) * 3072 + sl; }

    const ushort_t* h_src = isI ? hbf_u : hbf_i;
    const ushort_t* h_dst = isI ? hbf_i : hbf_u;
    const int*      nbr   = isI ? item_nbr  : user_nbr;
    const int*      times = isI ? item_time : user_time;
    const ushort_t* teA   = isI ? teA_i : teA_u;
    ushort_t*       ccout = isI ? cc_i  : cc_u;
    const int n = nodeblk * 2 + wid;

    char*  mailb = SM[wid];                   // [50 rows][128 B], granule-swizzled
    float* EB    = (float*)(SM[wid] + 6400);  // e[64] e1[64] tp[64]
    const int c = lane & 15;
    const int g = lane >> 4;

    int my_t = 0, my_nb = 0;
    if (lane < KK) {
        my_t  = times[n * KK + lane];
        my_nb = nbr[n * KK + lane];
    }

    // ---- gather register A-frags (verified layout) + LDS mail copy ----
    u32x4 af[4][2];
    #pragma unroll
    for (int t = 0; t < 4; ++t) {
        int r = t * 16 + c;
        int idx = __builtin_amdgcn_ds_bpermute(r << 2, my_nb);
        const ushort_t* src = h_src + idx * DH;
        #pragma unroll
        for (int s = 0; s < 2; ++s) {
            u32x4 v = *(const u32x4*)(src + s * 32 + g * 8);
            af[t][s] = v;
            if (t < 3 || c < 2) {   // rows < 50 only
                unsigned bo = (unsigned)(r * 128)
                            + (unsigned)(((4 * s + g) ^ (c & 7)) << 4);
                *(u32x4*)(mailb + bo) = v;
            }
        }
    }

    // ---- stable ranks ----
    int key = my_t * 64 + lane;
    int sro = 0;
    #pragma unroll
    for (int j = 0; j < KK; ++j) {
        int kj = __builtin_amdgcn_readlane(key, j);
        sro += (kj > key) ? 1 : 0;
    }

    // ---- last = first argmax(times) ----
    int key2 = (lane < KK) ? (my_t * 64 + (63 - lane)) : -1;
    #pragma unroll
    for (int off = 32; off >= 1; off >>= 1) {
        int o = __shfl_xor(key2, off);
        key2 = key2 > o ? key2 : o;
    }
    const int last = __builtin_amdgcn_readfirstlane(63 - (key2 & 63));

    // ---- B-fragments: col0 = dst(bf16), col1 = sle = mail[last] from LDS ----
    u32x4 fbv[2];
    {
        const ushort_t* hd = h_dst + n * DH;
        #pragma unroll
        for (int s = 0; s < 2; ++s) {
            u32x4 dp = *(const u32x4*)(hd + s * 32 + g * 8);
            unsigned sbyte = (unsigned)(last * 128)
                           + (unsigned)((((4 * s + g) ^ (last & 7)) << 4));
            u32x4 sl2 = *(const u32x4*)(mailb + sbyte);
            fbv[s] = (c == 1) ? sl2 : dp;
        }
    }

    // ---- dot MFMA: e (col0), e1 (col1) ----
    #pragma unroll
    for (int t = 0; t < 4; ++t) {
        f32x4 acc = {0.f, 0.f, 0.f, 0.f};
        #pragma unroll
        for (int s = 0; s < 2; ++s)
            acc = __builtin_amdgcn_mfma_f32_16x16x32_bf16(as_bf(af[t][s]), as_bf(fbv[s]), acc, 0, 0, 0);
        if (c < 2) {
            float* eb = EB + c * 64 + t * 16 + g * 4;
            eb[0] = acc[0]; eb[1] = acc[1]; eb[2] = acc[2]; eb[3] = acc[3];
        }
    }

    // ---- tp MFMA (teA tiles) ----
    #pragma unroll
    for (int t = 0; t < 4; ++t) {
        f32x4 acc = {0.f, 0.f, 0.f, 0.f};
        #pragma unroll
        for (int s = 0; s < 2; ++s) {
            u32x4 ta = *(const u32x4*)(teA + ((t * 2 + s) * 64 + lane) * 8);
            acc = __builtin_amdgcn_mfma_f32_16x16x32_bf16(as_bf(ta), as_bf(fbv[s]), acc, 0, 0, 0);
        }
        if (c == 0) {
            float* eb = EB + 128 + t * 16 + g * 4;
            eb[0] = acc[0]; eb[1] = acc[1]; eb[2] = acc[2]; eb[3] = acc[3];
        }
    }

    // ---- softmax at lane = k ----
    float eraw  = EB[lane];
    float e1raw = EB[64 + lane];
    float tpown = EB[128 + lane];
    float tps = __uint_as_float(__builtin_amdgcn_ds_bpermute(sro << 2, __float_as_uint(tpown)));
    float e  = (lane < KK) ? (eraw + tps) * 0.125f : -INFINITY;
    float e1 = (lane < KK) ? e1raw * 0.125f        : -INFINITY;
    float m = e, m1 = e1;
    #pragma unroll
    for (int off = 32; off >= 1; off >>= 1) {
        m  = fmaxf(m,  __shfl_xor(m,  off));
        m1 = fmaxf(m1, __shfl_xor(m1, off));
    }
    float p  = (lane < KK) ? __expf(e - m)   : 0.f;
    float p1 = (lane < KK) ? __expf(e1 - m1) : 0.f;
    float s = p, s1 = p1;
    #pragma unroll
    for (int off = 32; off >= 1; off >>= 1) {
        s  += __shfl_xor(s,  off);
        s1 += __shfl_xor(s1, off);
    }
    float al  = p  * __builtin_amdgcn_rcpf(s);
    float al1 = p1 * __builtin_amdgcn_rcpf(s1);

    // ---- beta scatter + cc store ----
    ushort_t* ccr = ccout + (size_t)n * 192;
    {
        int pushaddr = ((lane < KK) ? sro : lane) << 2;
        float beta = __uint_as_float(__builtin_amdgcn_ds_permute(pushaddr, __float_as_uint(al)));
        ccr[128 + lane] = bf16r(beta);
    }

    // ---- weighted sums (lane = d): LDS mail reads + f32 dual-readlane alphas ----
    int voff[8];
    #pragma unroll
    for (int q = 0; q < 8; ++q)
        voff[q] = (((lane >> 3) ^ q) << 4) + (lane & 7) * 2;
    float hl = 0.f, hs = 0.f;
    #pragma unroll
    for (int k = 0; k < KK; ++k) {
        float a  = __uint_as_float(__builtin_amdgcn_readlane(__float_as_uint(al),  k));
        float a1 = __uint_as_float(__builtin_amdgcn_readlane(__float_as_uint(al1), k));
        ushort_t u = *(const ushort_t*)(mailb + k * 128 + voff[k & 7]);
        float mv = __uint_as_float(((unsigned)u) << 16);
        hl = fmaf(a,  mv, hl);
        hs = fmaf(a1, mv, hs);
    }
    unsigned hp = cvtpk(hl, hs);
    ccr[lane]      = (ushort_t)hp;
    ccr[64 + lane] = (ushort_t)(hp >> 16);
}

// ---------------------------------------------------------------------------
// epi: combined item+user batched gate GEMM. 1 wave = 16 nodes.
// (byte-identical to R12/R13/R14 — verified)
// ---------------------------------------------------------------------------
__global__ __launch_bounds__(256) void epi_kernel(
    const ushort_t* __restrict__ cc_i, const ushort_t* __restrict__ cc_u,
    const ushort_t* __restrict__ gA_i, const ushort_t* __restrict__ gA_u,
    const float* __restrict__ item_feat, const float* __restrict__ user_feat,
    float* __restrict__ item_out, float* __restrict__ user_out)
{
    const int b = blockIdx.x;
    const bool isU = b >= (NI / 64);
    const ushort_t* cc   = isU ? cc_u : cc_i;
    const ushort_t* gA   = isU ? gA_u : gA_i;
    const float*    feat = isU ? user_feat : item_feat;
    float*          out  = isU ? user_out  : item_out;
    const int bb = isU ? b - NI / 64 : b;

    const int w    = threadIdx.x >> 6;
    const int lane = threadIdx.x & 63;
    const int c = lane & 15, g = lane >> 4;
    const int nb = bb * 64 + w * 16;

    const char* ccr = (const char*)(cc + (size_t)(nb + c) * 192);
    u32x4 bb6[6];
    #pragma unroll
    for (int s = 0; s < 6; ++s)
        bb6[s] = *(const u32x4*)(ccr + s * 64 + g * 16);

    f32x4 acc[4] = {{0,0,0,0},{0,0,0,0},{0,0,0,0},{0,0,0,0}};
    #pragma unroll
    for (int mt = 0; mt < 4; ++mt)
        #pragma unroll
        for (int s = 0; s < 6; ++s) {
            u32x4 ga = *(const u32x4*)(gA + (size_t)((mt * 6 + s) * 64 + lane) * 8);
            acc[mt] = __builtin_amdgcn_mfma_f32_16x16x32_bf16(as_bf(ga), as_bf(bb6[s]), acc[mt], 0, 0, 0);
        }

    const float* fr   = feat + (size_t)(nb + c) * 64;
    float*       orow = out  + (size_t)(nb + c) * 64;
    #pragma unroll
    for (int mt = 0; mt < 4; ++mt) {
        float4 f4 = *(const float4*)(fr + mt * 16 + g * 4);
        float4 o;
        float v0 = acc[mt][0] + f4.x; o.x = v0 > 0.f ? v0 : (__expf(v0) - 1.f);
        float v1 = acc[mt][1] + f4.y; o.y = v1 > 0.f ? v1 : (__expf(v1) - 1.f);
        float v2 = acc[mt][2] + f4.z; o.z = v2 > 0.f ? v2 : (__expf(v2) - 1.f);
        float v3 = acc[mt][3] + f4.w; o.w = v3 > 0.f ? v3 : (__expf(v3) - 1.f);
        *(float4*)(orow + mt * 16 + g * 4) = o;
    }
}

extern "C" void kernel_launch(void* const* d_in, const int* in_sizes, int n_in,
                              void* d_out, int out_size, void* d_ws, size_t ws_size,
                              hipStream_t stream) {
    const float* user_feat = (const float*)d_in[0];
    const float* item_feat = (const float*)d_in[1];
    const float* W_user    = (const float*)d_in[2];
    const float* W_item    = (const float*)d_in[3];
    const float* gate_u    = (const float*)d_in[4];
    const float* gate_i    = (const float*)d_in[5];
    const float* u_te      = (const float*)d_in[6];
    const float* u_te_k    = (const float*)d_in[7];
    const float* i_te      = (const float*)d_in[8];
    const float* i_te_k    = (const float*)d_in[9];
    const int*   user_nbr  = (const int*)d_in[10];
    const int*   item_nbr  = (const int*)d_in[11];
    const int*   user_time = (const int*)d_in[12];
    const int*   item_time = (const int*)d_in[13];

    ushort_t* hbf_u = (ushort_t*)d_ws;            // NU*64
    ushort_t* hbf_i = hbf_u + NU * DH;            // NI*64
    ushort_t* teA_u = hbf_i + NI * DH;            // 4096
    ushort_t* teA_i = teA_u + 4096;               // 4096
    ushort_t* gA_u  = teA_i + 4096;               // 12288
    ushort_t* gA_i  = gA_u + 12288;               // 12288
    ushort_t* cc_i  = gA_i + 12288;               // NI*192
    ushort_t* cc_u  = cc_i + (size_t)NI * 192;    // NU*192

    float* user_out = (float*)d_out;
    float* item_out = user_out + NU * DH;

    hipLaunchKernelGGL(projprep_kernel, dim3(770), dim3(256), 0, stream,
                       user_feat, item_feat, W_user, W_item, gate_u, gate_i,
                       u_te, i_te, u_te_k, i_te_k,
                       hbf_u, hbf_i, teA_u, teA_i, gA_u, gA_i);
    hipLaunchKernelGGL(agg_kernel, dim3(NI / 2 + NU / 2), dim3(128), 0, stream,
                       hbf_u, hbf_i, item_nbr, item_time, user_nbr, user_time,
                       teA_u, teA_i, cc_i, cc_u);
    hipLaunchKernelGGL(epi_kernel, dim3(NI / 64 + NU / 64), dim3(256), 0, stream,
                       cc_i, cc_u, gA_i, gA_u, item_feat, user_feat,
                       item_out, user_out);
}